// Round 1
// baseline (977.599 us; speedup 1.0000x reference)
//
#include <hip/hip_runtime.h>

constexpr int N_NODES = 100000;
constexpr int N_EDGES = 1000000;
constexpr int D = 64;

// 16 threads per edge, one float4 chunk each.
// Coalesced gather of features[src], weight-scale, 4 global fp32 atomics to agg[dst].
__global__ __launch_bounds__(256) void scatter_k(
    const float* __restrict__ feat,
    const int*   __restrict__ ei,
    const float* __restrict__ ew,
    float*       __restrict__ agg)
{
    int gid = blockIdx.x * 256 + threadIdx.x;
    int e = gid >> 4;
    if (e >= N_EDGES) return;
    int c = (gid & 15) * 4;

    int   src = ei[e];
    int   dst = ei[N_EDGES + e];
    float w   = ew[e];

    float4 f = *reinterpret_cast<const float4*>(feat + (size_t)src * D + c);
    float* a = agg + (size_t)dst * D + c;
    atomicAdd(a + 0, f.x * w);
    atomicAdd(a + 1, f.y * w);
    atomicAdd(a + 2, f.z * w);
    atomicAdd(a + 3, f.w * w);
}

// out[n][o] = sum_i (agg[n][i] + feat[n][i]) * W[o][i] + b[o]
// lane = o (64 lanes), wave = one node, 4 nodes/block.
// W in LDS, pitch 68: float4 row reads are bank-even (lane o -> bank group 4*(o%8)).
// x row in LDS, float4 broadcast reads (conflict-free).
// Safe to run in-place (agg == out): each block reads only rows n..n+3 before writing them.
__global__ __launch_bounds__(256) void gemm_k(
    const float* __restrict__ agg,
    const float* __restrict__ feat,
    const float* __restrict__ W,
    const float* __restrict__ bias,
    float*       __restrict__ out)
{
    constexpr int PITCH = 68;
    __shared__ float Wl[D * PITCH];
    __shared__ float xs[4][D];

    int tid = threadIdx.x;
    for (int i = tid; i < D * D; i += 256) {
        Wl[(i >> 6) * PITCH + (i & 63)] = W[i];
    }

    int o  = tid & 63;
    int wv = tid >> 6;
    int n  = blockIdx.x * 4 + wv;
    float b = bias[o];

    if (n < N_NODES)
        xs[wv][o] = agg[(size_t)n * D + o] + feat[(size_t)n * D + o];
    __syncthreads();
    if (n >= N_NODES) return;

    const float4* x4 = reinterpret_cast<const float4*>(&xs[wv][0]);
    const float4* w4 = reinterpret_cast<const float4*>(&Wl[o * PITCH]);
    float acc = b;
#pragma unroll
    for (int i = 0; i < 16; ++i) {
        float4 xv = x4[i];
        float4 wq = w4[i];
        acc += xv.x * wq.x + xv.y * wq.y + xv.z * wq.z + xv.w * wq.w;
    }
    out[(size_t)n * D + o] = acc;
}

extern "C" void kernel_launch(void* const* d_in, const int* in_sizes, int n_in,
                              void* d_out, int out_size, void* d_ws, size_t ws_size,
                              hipStream_t stream) {
    const float* feat = (const float*)d_in[0];
    const int*   ei   = (const int*)d_in[1];   // [2, E] int32, row 0 = src, row 1 = dst
    const float* ew   = (const float*)d_in[2];
    const float* W    = (const float*)d_in[3]; // [D_OUT, D_IN]
    const float* b    = (const float*)d_in[4];
    float*       out  = (float*)d_out;

    const size_t agg_bytes = (size_t)N_NODES * D * sizeof(float);
    // Prefer workspace for the accumulator; fall back to in-place via d_out
    // (in-place is safe for gemm_k — see kernel comment).
    float* agg = (ws_size >= agg_bytes) ? (float*)d_ws : out;

    hipMemsetAsync(agg, 0, agg_bytes, stream);

    scatter_k<<<(N_EDGES * 16) / 256, 256, 0, stream>>>(feat, ei, ew, agg);
    gemm_k<<<(N_NODES + 3) / 4, 256, 0, stream>>>(agg, feat, W, b, out);
}

// Round 2
// 560.922 us; speedup vs baseline: 1.7428x; 1.7428x over previous
//
#include <hip/hip_runtime.h>

constexpr int N_NODES = 100000;
constexpr int N_EDGES = 1000000;
constexpr int D = 64;

// ---------------- sort-free fallback path (round-1, atomic scatter) --------

__global__ __launch_bounds__(256) void scatter_k(
    const float* __restrict__ feat,
    const int*   __restrict__ ei,
    const float* __restrict__ ew,
    float*       __restrict__ agg)
{
    int gid = blockIdx.x * 256 + threadIdx.x;
    int e = gid >> 4;
    if (e >= N_EDGES) return;
    int c = (gid & 15) * 4;

    int   src = ei[e];
    int   dst = ei[N_EDGES + e];
    float w   = ew[e];

    float4 f = *reinterpret_cast<const float4*>(feat + (size_t)src * D + c);
    float* a = agg + (size_t)dst * D + c;
    atomicAdd(a + 0, f.x * w);
    atomicAdd(a + 1, f.y * w);
    atomicAdd(a + 2, f.z * w);
    atomicAdd(a + 3, f.w * w);
}

__global__ __launch_bounds__(256) void gemm_k(
    const float* __restrict__ agg,
    const float* __restrict__ feat,
    const float* __restrict__ W,
    const float* __restrict__ bias,
    float*       __restrict__ out)
{
    constexpr int PITCH = 68;
    __shared__ float Wl[D * PITCH];
    __shared__ float xs[4][D];

    int tid = threadIdx.x;
    for (int i = tid; i < D * D; i += 256)
        Wl[(i >> 6) * PITCH + (i & 63)] = W[i];

    int o  = tid & 63;
    int wv = tid >> 6;
    int n  = blockIdx.x * 4 + wv;
    float b = bias[o];

    if (n < N_NODES)
        xs[wv][o] = agg[(size_t)n * D + o] + feat[(size_t)n * D + o];
    __syncthreads();
    if (n >= N_NODES) return;

    const float4* x4 = reinterpret_cast<const float4*>(&xs[wv][0]);
    const float4* w4 = reinterpret_cast<const float4*>(&Wl[o * PITCH]);
    float acc = b;
#pragma unroll
    for (int i = 0; i < 16; ++i) {
        float4 xv = x4[i];
        float4 wq = w4[i];
        acc += xv.x * wq.x + xv.y * wq.y + xv.z * wq.z + xv.w * wq.w;
    }
    out[(size_t)n * D + o] = acc;
}

// ---------------- counting-sort path --------------------------------------

// 1M int atomics over 100k counters.
__global__ __launch_bounds__(256) void hist_k(
    const int* __restrict__ ei, int* __restrict__ hist)
{
    int e = blockIdx.x * 256 + threadIdx.x;
    if (e >= N_EDGES) return;
    atomicAdd(&hist[ei[N_EDGES + e]], 1);
}

// Single-block exclusive scan over 100k counts.
// hist: in = counts, out = bucket start (cursor). offsets: pristine copy + total.
__global__ __launch_bounds__(1024) void scan_k(
    int* __restrict__ hist, int* __restrict__ offsets)
{
    constexpr int CHUNK = (N_NODES + 1023) / 1024;  // 98
    __shared__ int tsum[1024];
    int t  = threadIdx.x;
    int lo = t * CHUNK;
    int hi = min(lo + CHUNK, N_NODES);

    int s = 0;
    for (int i = lo; i < hi; ++i) s += hist[i];
    tsum[t] = s;
    __syncthreads();

    // Hillis-Steele inclusive scan in LDS.
    for (int d = 1; d < 1024; d <<= 1) {
        int v = (t >= d) ? tsum[t - d] : 0;
        __syncthreads();
        tsum[t] += v;
        __syncthreads();
    }

    int run = (t > 0) ? tsum[t - 1] : 0;  // exclusive base for this chunk
    for (int i = lo; i < hi; ++i) {
        int c = hist[i];
        offsets[i] = run;
        hist[i]    = run;   // becomes the reorder cursor
        run += c;
    }
    if (t == 1023) offsets[N_NODES] = run;  // == N_EDGES
}

// Bucket edges by dst: one packed 8 B record {src, bits(w)} per edge.
__global__ __launch_bounds__(256) void reorder_k(
    const int*   __restrict__ ei,
    const float* __restrict__ ew,
    int*         __restrict__ cursor,
    int2*        __restrict__ sorted_e)
{
    int e = blockIdx.x * 256 + threadIdx.x;
    if (e >= N_EDGES) return;
    int src = ei[e];
    int dst = ei[N_EDGES + e];
    int pos = atomicAdd(&cursor[dst], 1);
    sorted_e[pos] = make_int2(src, __float_as_int(ew[e]));
}

// Wave-per-node fused: aggregate (gather rows of feat) + residual + x @ W^T + b.
// N_NODES = 4 * 25000 exactly, so no tail guard needed and all threads reach
// the barrier.
__global__ __launch_bounds__(256) void agg_gemm_k(
    const float* __restrict__ feat,
    const int2*  __restrict__ sorted_e,
    const int*   __restrict__ offsets,
    const float* __restrict__ W,
    const float* __restrict__ bias,
    float*       __restrict__ out)
{
    constexpr int PITCH = 68;
    __shared__ float Wl[D * PITCH];
    __shared__ float xs[4][D];

    int tid = threadIdx.x;
    for (int i = tid; i < D * D; i += 256)
        Wl[(i >> 6) * PITCH + (i & 63)] = W[i];

    int lane = tid & 63;
    int wv   = tid >> 6;
    int n    = blockIdx.x * 4 + wv;

    float acc = feat[(size_t)n * D + lane];  // residual
    int lo = offsets[n], hi = offsets[n + 1];
    for (int j = lo; j < hi; ++j) {
        int2  er = sorted_e[j];                 // wave-uniform 8 B broadcast
        float w  = __int_as_float(er.y);
        acc += feat[(size_t)er.x * D + lane] * w;  // coalesced 256 B row
    }
    xs[wv][lane] = acc;
    __syncthreads();

    const float4* x4 = reinterpret_cast<const float4*>(&xs[wv][0]);
    const float4* w4 = reinterpret_cast<const float4*>(&Wl[lane * PITCH]);
    float o = bias[lane];
#pragma unroll
    for (int i = 0; i < 16; ++i) {
        float4 xv = x4[i];
        float4 wq = w4[i];
        o += xv.x * wq.x + xv.y * wq.y + xv.z * wq.z + xv.w * wq.w;
    }
    out[(size_t)n * D + lane] = o;
}

// ---------------- launch ---------------------------------------------------

extern "C" void kernel_launch(void* const* d_in, const int* in_sizes, int n_in,
                              void* d_out, int out_size, void* d_ws, size_t ws_size,
                              hipStream_t stream) {
    const float* feat = (const float*)d_in[0];
    const int*   ei   = (const int*)d_in[1];   // [2, E]: row 0 = src, row 1 = dst
    const float* ew   = (const float*)d_in[2];
    const float* W    = (const float*)d_in[3];
    const float* b    = (const float*)d_in[4];
    float*       out  = (float*)d_out;

    // ws layout: cursor[100352] | offsets[100352] | sorted_e[1M] (int2)
    constexpr size_t NPAD       = 100352;              // 100000 rounded up, keeps 8B align
    constexpr size_t CURSOR_OFF = 0;
    constexpr size_t OFFSET_OFF = NPAD * sizeof(int);
    constexpr size_t SORTED_OFF = 2 * NPAD * sizeof(int);
    constexpr size_t WS_NEEDED  = SORTED_OFF + (size_t)N_EDGES * sizeof(int2);

    if (ws_size >= WS_NEEDED) {
        int*  cursor   = (int*)((char*)d_ws + CURSOR_OFF);
        int*  offsets  = (int*)((char*)d_ws + OFFSET_OFF);
        int2* sorted_e = (int2*)((char*)d_ws + SORTED_OFF);

        hipMemsetAsync(cursor, 0, N_NODES * sizeof(int), stream);
        hist_k   <<<(N_EDGES + 255) / 256, 256, 0, stream>>>(ei, cursor);
        scan_k   <<<1, 1024, 0, stream>>>(cursor, offsets);
        reorder_k<<<(N_EDGES + 255) / 256, 256, 0, stream>>>(ei, ew, cursor, sorted_e);
        agg_gemm_k<<<N_NODES / 4, 256, 0, stream>>>(feat, sorted_e, offsets, W, b, out);
    } else {
        // Fallback: atomic scatter, accumulate in d_out in-place.
        const size_t agg_bytes = (size_t)N_NODES * D * sizeof(float);
        float* agg = (ws_size >= agg_bytes) ? (float*)d_ws : out;
        hipMemsetAsync(agg, 0, agg_bytes, stream);
        scatter_k<<<(N_EDGES * 16) / 256, 256, 0, stream>>>(feat, ei, ew, agg);
        gemm_k<<<(N_NODES + 3) / 4, 256, 0, stream>>>(agg, feat, W, b, out);
    }
}

// Round 3
// 342.052 us; speedup vs baseline: 2.8580x; 1.6399x over previous
//
#include <hip/hip_runtime.h>

constexpr int N_NODES = 100000;
constexpr int N_EDGES = 1000000;
constexpr int D = 64;
constexpr int NTILES = (N_NODES + 1023) / 1024;  // 98

// ---------------- counting-sort path --------------------------------------

// 1M int atomics over 100k counters.
__global__ __launch_bounds__(256) void hist_k(
    const int* __restrict__ ei, int* __restrict__ hist)
{
    int e = blockIdx.x * 256 + threadIdx.x;
    if (e >= N_EDGES) return;
    atomicAdd(&hist[ei[N_EDGES + e]], 1);
}

// Phase 1: per-tile (1024 counts) sums. 98 blocks.
__global__ __launch_bounds__(256) void tile_sum_k(
    const int* __restrict__ counts, int* __restrict__ tileSums)
{
    __shared__ int red[256];
    int t = threadIdx.x;
    int base = blockIdx.x * 1024 + t * 4;
    int4 c = make_int4(0, 0, 0, 0);
    if (base + 3 < N_NODES) {
        c = *reinterpret_cast<const int4*>(counts + base);
    } else {
        if (base + 0 < N_NODES) c.x = counts[base + 0];
        if (base + 1 < N_NODES) c.y = counts[base + 1];
        if (base + 2 < N_NODES) c.z = counts[base + 2];
        if (base + 3 < N_NODES) c.w = counts[base + 3];
    }
    red[t] = c.x + c.y + c.z + c.w;
    __syncthreads();
    for (int d = 128; d > 0; d >>= 1) {
        if (t < d) red[t] += red[t + d];
        __syncthreads();
    }
    if (t == 0) tileSums[blockIdx.x] = red[0];
}

// Phase 2: exclusive scan of the 98 tile sums. One tiny block.
__global__ __launch_bounds__(128) void tile_scan_k(
    const int* __restrict__ tileSums, int* __restrict__ tileBase)
{
    __shared__ int s[128];
    int t = threadIdx.x;
    s[t] = (t < NTILES) ? tileSums[t] : 0;
    __syncthreads();
    for (int d = 1; d < 128; d <<= 1) {
        int v = (t >= d) ? s[t - d] : 0;
        __syncthreads();
        s[t] += v;
        __syncthreads();
    }
    if (t < NTILES) tileBase[t] = t ? s[t - 1] : 0;
}

// Phase 3: within-tile scan + tile base -> offsets[] and cursor[] (in-place
// over counts; each thread reads then rewrites only its own 4 elements).
__global__ __launch_bounds__(256) void scan_apply_k(
    int* __restrict__ counts, const int* __restrict__ tileBase,
    int* __restrict__ offsets)
{
    __shared__ int tsum[256];
    int t = threadIdx.x;
    int base = blockIdx.x * 1024 + t * 4;
    int4 c = make_int4(0, 0, 0, 0);
    bool full = (base + 3 < N_NODES);
    if (full) {
        c = *reinterpret_cast<const int4*>(counts + base);
    } else {
        if (base + 0 < N_NODES) c.x = counts[base + 0];
        if (base + 1 < N_NODES) c.y = counts[base + 1];
        if (base + 2 < N_NODES) c.z = counts[base + 2];
        if (base + 3 < N_NODES) c.w = counts[base + 3];
    }
    tsum[t] = c.x + c.y + c.z + c.w;
    __syncthreads();
    for (int d = 1; d < 256; d <<= 1) {
        int v = (t >= d) ? tsum[t - d] : 0;
        __syncthreads();
        tsum[t] += v;
        __syncthreads();
    }
    int run = tileBase[blockIdx.x] + (t ? tsum[t - 1] : 0);
    int4 o = make_int4(run, run + c.x, run + c.x + c.y, run + c.x + c.y + c.z);
    if (full) {
        *reinterpret_cast<int4*>(offsets + base) = o;
        *reinterpret_cast<int4*>(counts  + base) = o;
    } else {
        if (base + 0 < N_NODES) { offsets[base + 0] = o.x; counts[base + 0] = o.x; }
        if (base + 1 < N_NODES) { offsets[base + 1] = o.y; counts[base + 1] = o.y; }
        if (base + 2 < N_NODES) { offsets[base + 2] = o.z; counts[base + 2] = o.z; }
        if (base + 3 < N_NODES) { offsets[base + 3] = o.w; counts[base + 3] = o.w; }
    }
    if (blockIdx.x == 0 && t == 0) offsets[N_NODES] = N_EDGES;
}

// Bucket edges by dst: one packed 8 B record {src, bits(w)} per edge.
__global__ __launch_bounds__(256) void reorder_k(
    const int*   __restrict__ ei,
    const float* __restrict__ ew,
    int*         __restrict__ cursor,
    int2*        __restrict__ sorted_e)
{
    int e = blockIdx.x * 256 + threadIdx.x;
    if (e >= N_EDGES) return;
    int src = ei[e];
    int dst = ei[N_EDGES + e];
    int pos = atomicAdd(&cursor[dst], 1);
    sorted_e[pos] = make_int2(src, __float_as_int(ew[e]));
}

// Wave-per-node fused: aggregate (gather rows of feat) + residual + x @ W^T + b.
// N_NODES = 4 * 25000 exactly -> no tail guard, all threads reach the barrier.
__global__ __launch_bounds__(256) void agg_gemm_k(
    const float* __restrict__ feat,
    const int2*  __restrict__ sorted_e,
    const int*   __restrict__ offsets,
    const float* __restrict__ W,
    const float* __restrict__ bias,
    float*       __restrict__ out)
{
    constexpr int PITCH = 68;
    __shared__ float Wl[D * PITCH];
    __shared__ float xs[4][D];

    int tid = threadIdx.x;
    for (int i = tid; i < D * D; i += 256)
        Wl[(i >> 6) * PITCH + (i & 63)] = W[i];

    int lane = tid & 63;
    int wv   = tid >> 6;
    int n    = blockIdx.x * 4 + wv;

    float acc = feat[(size_t)n * D + lane];  // residual
    int lo = offsets[n], hi = offsets[n + 1];
    for (int j = lo; j < hi; ++j) {
        int2  er = sorted_e[j];                    // wave-uniform 8 B broadcast
        float w  = __int_as_float(er.y);
        acc += feat[(size_t)er.x * D + lane] * w;  // coalesced 256 B row
    }
    xs[wv][lane] = acc;
    __syncthreads();

    const float4* x4 = reinterpret_cast<const float4*>(&xs[wv][0]);
    const float4* w4 = reinterpret_cast<const float4*>(&Wl[lane * PITCH]);
    float o = bias[lane];
#pragma unroll
    for (int i = 0; i < 16; ++i) {
        float4 xv = x4[i];
        float4 wq = w4[i];
        o += xv.x * wq.x + xv.y * wq.y + xv.z * wq.z + xv.w * wq.w;
    }
    out[(size_t)n * D + lane] = o;
}

// ---------------- fallback path (round-1, atomic scatter) ------------------

__global__ __launch_bounds__(256) void scatter_k(
    const float* __restrict__ feat,
    const int*   __restrict__ ei,
    const float* __restrict__ ew,
    float*       __restrict__ agg)
{
    int gid = blockIdx.x * 256 + threadIdx.x;
    int e = gid >> 4;
    if (e >= N_EDGES) return;
    int c = (gid & 15) * 4;
    int   src = ei[e];
    int   dst = ei[N_EDGES + e];
    float w   = ew[e];
    float4 f = *reinterpret_cast<const float4*>(feat + (size_t)src * D + c);
    float* a = agg + (size_t)dst * D + c;
    atomicAdd(a + 0, f.x * w);
    atomicAdd(a + 1, f.y * w);
    atomicAdd(a + 2, f.z * w);
    atomicAdd(a + 3, f.w * w);
}

__global__ __launch_bounds__(256) void gemm_k(
    const float* __restrict__ agg,
    const float* __restrict__ feat,
    const float* __restrict__ W,
    const float* __restrict__ bias,
    float*       __restrict__ out)
{
    constexpr int PITCH = 68;
    __shared__ float Wl[D * PITCH];
    __shared__ float xs[4][D];
    int tid = threadIdx.x;
    for (int i = tid; i < D * D; i += 256)
        Wl[(i >> 6) * PITCH + (i & 63)] = W[i];
    int o  = tid & 63;
    int wv = tid >> 6;
    int n  = blockIdx.x * 4 + wv;
    float b = bias[o];
    if (n < N_NODES)
        xs[wv][o] = agg[(size_t)n * D + o] + feat[(size_t)n * D + o];
    __syncthreads();
    if (n >= N_NODES) return;
    const float4* x4 = reinterpret_cast<const float4*>(&xs[wv][0]);
    const float4* w4 = reinterpret_cast<const float4*>(&Wl[o * PITCH]);
    float acc = b;
#pragma unroll
    for (int i = 0; i < 16; ++i) {
        float4 xv = x4[i];
        float4 wq = w4[i];
        acc += xv.x * wq.x + xv.y * wq.y + xv.z * wq.z + xv.w * wq.w;
    }
    out[(size_t)n * D + o] = acc;
}

// ---------------- launch ---------------------------------------------------

extern "C" void kernel_launch(void* const* d_in, const int* in_sizes, int n_in,
                              void* d_out, int out_size, void* d_ws, size_t ws_size,
                              hipStream_t stream) {
    const float* feat = (const float*)d_in[0];
    const int*   ei   = (const int*)d_in[1];   // [2, E]: row 0 = src, row 1 = dst
    const float* ew   = (const float*)d_in[2];
    const float* W    = (const float*)d_in[3];
    const float* b    = (const float*)d_in[4];
    float*       out  = (float*)d_out;

    // ws layout: cursor[100352] | offsets[100352] | sorted_e[1M] (int2)
    // tileSums/tileBase live in cursor[]'s padding (ints 100096.. and 100224..).
    constexpr size_t NPAD       = 100352;
    constexpr size_t CURSOR_OFF = 0;
    constexpr size_t OFFSET_OFF = NPAD * sizeof(int);
    constexpr size_t SORTED_OFF = 2 * NPAD * sizeof(int);
    constexpr size_t WS_NEEDED  = SORTED_OFF + (size_t)N_EDGES * sizeof(int2);

    if (ws_size >= WS_NEEDED) {
        int*  cursor   = (int*)((char*)d_ws + CURSOR_OFF);
        int*  offsets  = (int*)((char*)d_ws + OFFSET_OFF);
        int2* sorted_e = (int2*)((char*)d_ws + SORTED_OFF);
        int*  tileSums = cursor + 100096;   // 98 ints, inside cursor padding
        int*  tileBase = cursor + 100224;   // 98 ints, inside cursor padding

        hipMemsetAsync(cursor, 0, N_NODES * sizeof(int), stream);
        hist_k     <<<(N_EDGES + 255) / 256, 256, 0, stream>>>(ei, cursor);
        tile_sum_k <<<NTILES, 256, 0, stream>>>(cursor, tileSums);
        tile_scan_k<<<1, 128, 0, stream>>>(tileSums, tileBase);
        scan_apply_k<<<NTILES, 256, 0, stream>>>(cursor, tileBase, offsets);
        reorder_k  <<<(N_EDGES + 255) / 256, 256, 0, stream>>>(ei, ew, cursor, sorted_e);
        agg_gemm_k <<<N_NODES / 4, 256, 0, stream>>>(feat, sorted_e, offsets, W, b, out);
    } else {
        const size_t agg_bytes = (size_t)N_NODES * D * sizeof(float);
        float* agg = (ws_size >= agg_bytes) ? (float*)d_ws : out;
        hipMemsetAsync(agg, 0, agg_bytes, stream);
        scatter_k<<<(N_EDGES * 16) / 256, 256, 0, stream>>>(feat, ei, ew, agg);
        gemm_k<<<(N_NODES + 3) / 4, 256, 0, stream>>>(agg, feat, W, b, out);
    }
}

// Round 5
// 251.701 us; speedup vs baseline: 3.8840x; 1.3590x over previous
//
#include <hip/hip_runtime.h>

constexpr int N_NODES = 100000;
constexpr int N_EDGES = 1000000;
constexpr int D = 64;
constexpr int NTILES = (N_NODES + 1023) / 1024;  // 98

// ---------------- counting-sort path --------------------------------------

// 1M int atomics over 100k counters.
__global__ __launch_bounds__(256) void hist_k(
    const int* __restrict__ ei, int* __restrict__ hist)
{
    int e = blockIdx.x * 256 + threadIdx.x;
    if (e >= N_EDGES) return;
    atomicAdd(&hist[ei[N_EDGES + e]], 1);
}

// Phase 1: per-tile (1024 counts) sums. 98 blocks.
__global__ __launch_bounds__(256) void tile_sum_k(
    const int* __restrict__ counts, int* __restrict__ tileSums)
{
    __shared__ int red[256];
    int t = threadIdx.x;
    int base = blockIdx.x * 1024 + t * 4;
    int4 c = make_int4(0, 0, 0, 0);
    if (base + 3 < N_NODES) {
        c = *reinterpret_cast<const int4*>(counts + base);
    } else {
        if (base + 0 < N_NODES) c.x = counts[base + 0];
        if (base + 1 < N_NODES) c.y = counts[base + 1];
        if (base + 2 < N_NODES) c.z = counts[base + 2];
        if (base + 3 < N_NODES) c.w = counts[base + 3];
    }
    red[t] = c.x + c.y + c.z + c.w;
    __syncthreads();
    for (int d = 128; d > 0; d >>= 1) {
        if (t < d) red[t] += red[t + d];
        __syncthreads();
    }
    if (t == 0) tileSums[blockIdx.x] = red[0];
}

// Phase 2: exclusive scan of the 98 tile sums. One tiny block.
__global__ __launch_bounds__(128) void tile_scan_k(
    const int* __restrict__ tileSums, int* __restrict__ tileBase)
{
    __shared__ int s[128];
    int t = threadIdx.x;
    s[t] = (t < NTILES) ? tileSums[t] : 0;
    __syncthreads();
    for (int d = 1; d < 128; d <<= 1) {
        int v = (t >= d) ? s[t - d] : 0;
        __syncthreads();
        s[t] += v;
        __syncthreads();
    }
    if (t < NTILES) tileBase[t] = t ? s[t - 1] : 0;
}

// Phase 3: within-tile scan + tile base -> offsets[] and cursor[].
__global__ __launch_bounds__(256) void scan_apply_k(
    int* __restrict__ counts, const int* __restrict__ tileBase,
    int* __restrict__ offsets)
{
    __shared__ int tsum[256];
    int t = threadIdx.x;
    int base = blockIdx.x * 1024 + t * 4;
    int4 c = make_int4(0, 0, 0, 0);
    bool full = (base + 3 < N_NODES);
    if (full) {
        c = *reinterpret_cast<const int4*>(counts + base);
    } else {
        if (base + 0 < N_NODES) c.x = counts[base + 0];
        if (base + 1 < N_NODES) c.y = counts[base + 1];
        if (base + 2 < N_NODES) c.z = counts[base + 2];
        if (base + 3 < N_NODES) c.w = counts[base + 3];
    }
    tsum[t] = c.x + c.y + c.z + c.w;
    __syncthreads();
    for (int d = 1; d < 256; d <<= 1) {
        int v = (t >= d) ? tsum[t - d] : 0;
        __syncthreads();
        tsum[t] += v;
        __syncthreads();
    }
    int run = tileBase[blockIdx.x] + (t ? tsum[t - 1] : 0);
    int4 o = make_int4(run, run + c.x, run + c.x + c.y, run + c.x + c.y + c.z);
    if (full) {
        *reinterpret_cast<int4*>(offsets + base) = o;
        *reinterpret_cast<int4*>(counts  + base) = o;
    } else {
        if (base + 0 < N_NODES) { offsets[base + 0] = o.x; counts[base + 0] = o.x; }
        if (base + 1 < N_NODES) { offsets[base + 1] = o.y; counts[base + 1] = o.y; }
        if (base + 2 < N_NODES) { offsets[base + 2] = o.z; counts[base + 2] = o.z; }
        if (base + 3 < N_NODES) { offsets[base + 3] = o.w; counts[base + 3] = o.w; }
    }
    if (blockIdx.x == 0 && t == 0) offsets[N_NODES] = N_EDGES;
}

// Bucket edges by dst: one packed 8 B record {src, bits(w)} per edge.
__global__ __launch_bounds__(256) void reorder_k(
    const int*   __restrict__ ei,
    const float* __restrict__ ew,
    int*         __restrict__ cursor,
    int2*        __restrict__ sorted_e)
{
    int e = blockIdx.x * 256 + threadIdx.x;
    if (e >= N_EDGES) return;
    int src = ei[e];
    int dst = ei[N_EDGES + e];
    int pos = atomicAdd(&cursor[dst], 1);
    sorted_e[pos] = make_int2(src, __float_as_int(ew[e]));
}

// Fused aggregate + residual + GEMM.
// Wave layout for aggregation: 4 groups of 16 lanes; group g handles edges
// k = 4*it+g, lane (g,sub) loads float4 chunk 'sub' of the source row ->
// one gather instruction covers 4 independent rows (4x MLP vs round-3).
// Edge records prefetched 64-wide per node, distributed via __shfl.
// CORRECTNESS (round-4 bug): the shfl loop trip count MUST be wave-uniform —
// ds_bpermute does not return data from EXEC-inactive source lanes. All 64
// lanes run niter iterations; only the load+FMA is predicated by k < cap.
__global__ __launch_bounds__(256) void agg_gemm_k(
    const float* __restrict__ feat,
    const int2*  __restrict__ sorted_e,
    const int*   __restrict__ offsets,
    const float* __restrict__ W,
    const float* __restrict__ bias,
    float*       __restrict__ out)
{
    constexpr int PITCH = 68;
    constexpr int NPB = 16;
    __shared__ float Wl[D * PITCH];
    __shared__ float xs[NPB][D];

    int tid = threadIdx.x;
    for (int i = tid; i < D * D; i += 256)
        Wl[(i >> 6) * PITCH + (i & 63)] = W[i];

    int lane = tid & 63;
    int wv   = tid >> 6;
    int g    = lane >> 4;   // edge group 0..3
    int sub  = lane & 15;   // float4 chunk 0..15

    for (int s = 0; s < 4; ++s) {
        int slot = wv * 4 + s;
        int n = blockIdx.x * NPB + slot;
        int lo = offsets[n], hi = offsets[n + 1];
        int deg = hi - lo;

        // Prefetch up to 64 edge records (coalesced, predicated).
        // Lanes >= deg hold {0, 0.0f} so an unguarded shfl of them is benign.
        int2 r = make_int2(0, 0);
        if (lo + lane < hi) r = sorted_e[lo + lane];

        float4 acc;
        if (g == 0)
            acc = *reinterpret_cast<const float4*>(feat + (size_t)n * D + sub * 4);
        else
            acc = make_float4(0.f, 0.f, 0.f, 0.f);

        int cap = deg < 64 ? deg : 64;
        int niter = (cap + 3) >> 2;          // wave-uniform trip count
        for (int it = 0; it < niter; ++it) {
            int k = it * 4 + g;
            int   src = __shfl(r.x, k);                     // all lanes active
            float w   = __int_as_float(__shfl(r.y, k));     // all lanes active
            if (k < cap) {
                float4 f = *reinterpret_cast<const float4*>(
                    feat + (size_t)src * D + sub * 4);
                acc.x = fmaf(f.x, w, acc.x);
                acc.y = fmaf(f.y, w, acc.y);
                acc.z = fmaf(f.z, w, acc.z);
                acc.w = fmaf(f.w, w, acc.w);
            }
        }
        // deg > 64 tail (statistically never at Poisson-10; per-lane loads,
        // no cross-lane ops -> divergence here is safe).
        for (int j = lo + 64 + g; j < hi; j += 4) {
            int2 er = sorted_e[j];
            float w = __int_as_float(er.y);
            float4 f = *reinterpret_cast<const float4*>(
                feat + (size_t)er.x * D + sub * 4);
            acc.x = fmaf(f.x, w, acc.x);
            acc.y = fmaf(f.y, w, acc.y);
            acc.z = fmaf(f.z, w, acc.z);
            acc.w = fmaf(f.w, w, acc.w);
        }

        // Reduce the 4 groups (all 64 lanes active here).
        acc.x += __shfl_xor(acc.x, 16);
        acc.y += __shfl_xor(acc.y, 16);
        acc.z += __shfl_xor(acc.z, 16);
        acc.w += __shfl_xor(acc.w, 16);
        acc.x += __shfl_xor(acc.x, 32);
        acc.y += __shfl_xor(acc.y, 32);
        acc.z += __shfl_xor(acc.z, 32);
        acc.w += __shfl_xor(acc.w, 32);

        if (g == 0)
            *reinterpret_cast<float4*>(&xs[slot][sub * 4]) = acc;
    }
    __syncthreads();

    // GEMM: wave wv computes its 4 nodes, lane = output column.
    const float4* w4 = reinterpret_cast<const float4*>(&Wl[lane * PITCH]);
    const float4* x0 = reinterpret_cast<const float4*>(&xs[wv * 4 + 0][0]);
    const float4* x1 = reinterpret_cast<const float4*>(&xs[wv * 4 + 1][0]);
    const float4* x2 = reinterpret_cast<const float4*>(&xs[wv * 4 + 2][0]);
    const float4* x3 = reinterpret_cast<const float4*>(&xs[wv * 4 + 3][0]);
    float b = bias[lane];
    float a0 = b, a1 = b, a2 = b, a3 = b;
#pragma unroll
    for (int i = 0; i < 16; ++i) {
        float4 wq = w4[i];
        float4 v0 = x0[i];
        float4 v1 = x1[i];
        float4 v2 = x2[i];
        float4 v3 = x3[i];
        a0 += v0.x * wq.x + v0.y * wq.y + v0.z * wq.z + v0.w * wq.w;
        a1 += v1.x * wq.x + v1.y * wq.y + v1.z * wq.z + v1.w * wq.w;
        a2 += v2.x * wq.x + v2.y * wq.y + v2.z * wq.z + v2.w * wq.w;
        a3 += v3.x * wq.x + v3.y * wq.y + v3.z * wq.z + v3.w * wq.w;
    }
    int nb = blockIdx.x * NPB + wv * 4;
    out[(size_t)(nb + 0) * D + lane] = a0;
    out[(size_t)(nb + 1) * D + lane] = a1;
    out[(size_t)(nb + 2) * D + lane] = a2;
    out[(size_t)(nb + 3) * D + lane] = a3;
}

// ---------------- fallback path (round-1, atomic scatter) ------------------

__global__ __launch_bounds__(256) void scatter_k(
    const float* __restrict__ feat,
    const int*   __restrict__ ei,
    const float* __restrict__ ew,
    float*       __restrict__ agg)
{
    int gid = blockIdx.x * 256 + threadIdx.x;
    int e = gid >> 4;
    if (e >= N_EDGES) return;
    int c = (gid & 15) * 4;
    int   src = ei[e];
    int   dst = ei[N_EDGES + e];
    float w   = ew[e];
    float4 f = *reinterpret_cast<const float4*>(feat + (size_t)src * D + c);
    float* a = agg + (size_t)dst * D + c;
    atomicAdd(a + 0, f.x * w);
    atomicAdd(a + 1, f.y * w);
    atomicAdd(a + 2, f.z * w);
    atomicAdd(a + 3, f.w * w);
}

__global__ __launch_bounds__(256) void gemm_k(
    const float* __restrict__ agg,
    const float* __restrict__ feat,
    const float* __restrict__ W,
    const float* __restrict__ bias,
    float*       __restrict__ out)
{
    constexpr int PITCH = 68;
    __shared__ float Wl[D * PITCH];
    __shared__ float xs[4][D];
    int tid = threadIdx.x;
    for (int i = tid; i < D * D; i += 256)
        Wl[(i >> 6) * PITCH + (i & 63)] = W[i];
    int o  = tid & 63;
    int wv = tid >> 6;
    int n  = blockIdx.x * 4 + wv;
    float b = bias[o];
    if (n < N_NODES)
        xs[wv][o] = agg[(size_t)n * D + o] + feat[(size_t)n * D + o];
    __syncthreads();
    if (n >= N_NODES) return;
    const float4* x4 = reinterpret_cast<const float4*>(&xs[wv][0]);
    const float4* w4 = reinterpret_cast<const float4*>(&Wl[o * PITCH]);
    float acc = b;
#pragma unroll
    for (int i = 0; i < 16; ++i) {
        float4 xv = x4[i];
        float4 wq = w4[i];
        acc += xv.x * wq.x + xv.y * wq.y + xv.z * wq.z + xv.w * wq.w;
    }
    out[(size_t)n * D + o] = acc;
}

// ---------------- launch ---------------------------------------------------

extern "C" void kernel_launch(void* const* d_in, const int* in_sizes, int n_in,
                              void* d_out, int out_size, void* d_ws, size_t ws_size,
                              hipStream_t stream) {
    const float* feat = (const float*)d_in[0];
    const int*   ei   = (const int*)d_in[1];   // [2, E]: row 0 = src, row 1 = dst
    const float* ew   = (const float*)d_in[2];
    const float* W    = (const float*)d_in[3];
    const float* b    = (const float*)d_in[4];
    float*       out  = (float*)d_out;

    constexpr size_t NPAD       = 100352;
    constexpr size_t CURSOR_OFF = 0;
    constexpr size_t OFFSET_OFF = NPAD * sizeof(int);
    constexpr size_t SORTED_OFF = 2 * NPAD * sizeof(int);
    constexpr size_t WS_NEEDED  = SORTED_OFF + (size_t)N_EDGES * sizeof(int2);

    if (ws_size >= WS_NEEDED) {
        int*  cursor   = (int*)((char*)d_ws + CURSOR_OFF);
        int*  offsets  = (int*)((char*)d_ws + OFFSET_OFF);
        int2* sorted_e = (int2*)((char*)d_ws + SORTED_OFF);
        int*  tileSums = cursor + 100096;   // 98 ints, inside cursor padding
        int*  tileBase = cursor + 100224;   // 98 ints, inside cursor padding

        hipMemsetAsync(cursor, 0, N_NODES * sizeof(int), stream);
        hist_k     <<<(N_EDGES + 255) / 256, 256, 0, stream>>>(ei, cursor);
        tile_sum_k <<<NTILES, 256, 0, stream>>>(cursor, tileSums);
        tile_scan_k<<<1, 128, 0, stream>>>(tileSums, tileBase);
        scan_apply_k<<<NTILES, 256, 0, stream>>>(cursor, tileBase, offsets);
        reorder_k  <<<(N_EDGES + 255) / 256, 256, 0, stream>>>(ei, ew, cursor, sorted_e);
        agg_gemm_k <<<N_NODES / 16, 256, 0, stream>>>(feat, sorted_e, offsets, W, b, out);
    } else {
        const size_t agg_bytes = (size_t)N_NODES * D * sizeof(float);
        float* agg = (ws_size >= agg_bytes) ? (float*)d_ws : out;
        hipMemsetAsync(agg, 0, agg_bytes, stream);
        scatter_k<<<(N_EDGES * 16) / 256, 256, 0, stream>>>(feat, ei, ew, agg);
        gemm_k<<<(N_NODES + 3) / 4, 256, 0, stream>>>(agg, feat, W, b, out);
    }
}

// Round 6
// 203.654 us; speedup vs baseline: 4.8003x; 1.2359x over previous
//
#include <hip/hip_runtime.h>

constexpr int N_NODES = 100000;
constexpr int N_EDGES = 1000000;
constexpr int D = 64;
constexpr int NTILES = (N_NODES + 1023) / 1024;  // 98

// ---------------- counting-sort (rank-fused) path --------------------------

// Fused histogram + rank: rank[e] = my slot within dst's bucket.
// 1M atomic-with-return over 100k counters + coalesced 4 B write.
__global__ __launch_bounds__(256) void rank_k(
    const int* __restrict__ ei, int* __restrict__ cnt, int* __restrict__ rank)
{
    int e = blockIdx.x * 256 + threadIdx.x;
    if (e >= N_EDGES) return;
    rank[e] = atomicAdd(&cnt[ei[N_EDGES + e]], 1);
}

// Plain histogram (tier-2 path).
__global__ __launch_bounds__(256) void hist_k(
    const int* __restrict__ ei, int* __restrict__ hist)
{
    int e = blockIdx.x * 256 + threadIdx.x;
    if (e >= N_EDGES) return;
    atomicAdd(&hist[ei[N_EDGES + e]], 1);
}

// Phase 1: per-tile (1024 counts) sums. 98 blocks.
__global__ __launch_bounds__(256) void tile_sum_k(
    const int* __restrict__ counts, int* __restrict__ tileSums)
{
    __shared__ int red[256];
    int t = threadIdx.x;
    int base = blockIdx.x * 1024 + t * 4;
    int4 c = make_int4(0, 0, 0, 0);
    if (base + 3 < N_NODES) {
        c = *reinterpret_cast<const int4*>(counts + base);
    } else {
        if (base + 0 < N_NODES) c.x = counts[base + 0];
        if (base + 1 < N_NODES) c.y = counts[base + 1];
        if (base + 2 < N_NODES) c.z = counts[base + 2];
        if (base + 3 < N_NODES) c.w = counts[base + 3];
    }
    red[t] = c.x + c.y + c.z + c.w;
    __syncthreads();
    for (int d = 128; d > 0; d >>= 1) {
        if (t < d) red[t] += red[t + d];
        __syncthreads();
    }
    if (t == 0) tileSums[blockIdx.x] = red[0];
}

// Phase 2: exclusive scan of the 98 tile sums. One tiny block.
__global__ __launch_bounds__(128) void tile_scan_k(
    const int* __restrict__ tileSums, int* __restrict__ tileBase)
{
    __shared__ int s[128];
    int t = threadIdx.x;
    s[t] = (t < NTILES) ? tileSums[t] : 0;
    __syncthreads();
    for (int d = 1; d < 128; d <<= 1) {
        int v = (t >= d) ? s[t - d] : 0;
        __syncthreads();
        s[t] += v;
        __syncthreads();
    }
    if (t < NTILES) tileBase[t] = t ? s[t - 1] : 0;
}

// Phase 3: within-tile scan + tile base -> offsets[] (and cursor-ified
// counts[], used only by the tier-2 reorder path; harmless otherwise).
__global__ __launch_bounds__(256) void scan_apply_k(
    int* __restrict__ counts, const int* __restrict__ tileBase,
    int* __restrict__ offsets)
{
    __shared__ int tsum[256];
    int t = threadIdx.x;
    int base = blockIdx.x * 1024 + t * 4;
    int4 c = make_int4(0, 0, 0, 0);
    bool full = (base + 3 < N_NODES);
    if (full) {
        c = *reinterpret_cast<const int4*>(counts + base);
    } else {
        if (base + 0 < N_NODES) c.x = counts[base + 0];
        if (base + 1 < N_NODES) c.y = counts[base + 1];
        if (base + 2 < N_NODES) c.z = counts[base + 2];
        if (base + 3 < N_NODES) c.w = counts[base + 3];
    }
    tsum[t] = c.x + c.y + c.z + c.w;
    __syncthreads();
    for (int d = 1; d < 256; d <<= 1) {
        int v = (t >= d) ? tsum[t - d] : 0;
        __syncthreads();
        tsum[t] += v;
        __syncthreads();
    }
    int run = tileBase[blockIdx.x] + (t ? tsum[t - 1] : 0);
    int4 o = make_int4(run, run + c.x, run + c.x + c.y, run + c.x + c.y + c.z);
    if (full) {
        *reinterpret_cast<int4*>(offsets + base) = o;
        *reinterpret_cast<int4*>(counts  + base) = o;
    } else {
        if (base + 0 < N_NODES) { offsets[base + 0] = o.x; counts[base + 0] = o.x; }
        if (base + 1 < N_NODES) { offsets[base + 1] = o.y; counts[base + 1] = o.y; }
        if (base + 2 < N_NODES) { offsets[base + 2] = o.z; counts[base + 2] = o.z; }
        if (base + 3 < N_NODES) { offsets[base + 3] = o.w; counts[base + 3] = o.w; }
    }
    if (blockIdx.x == 0 && t == 0) offsets[N_NODES] = N_EDGES;
}

// Atomic-free placement: pos = offsets[dst] + rank[e]. Coalesced reads,
// one scattered 8 B store (the unavoidable part of any dst-sort).
__global__ __launch_bounds__(256) void place_k(
    const int*   __restrict__ ei,
    const float* __restrict__ ew,
    const int*   __restrict__ rank,
    const int*   __restrict__ offsets,
    int2*        __restrict__ sorted_e)
{
    int e = blockIdx.x * 256 + threadIdx.x;
    if (e >= N_EDGES) return;
    int dst = ei[N_EDGES + e];
    int pos = offsets[dst] + rank[e];
    sorted_e[pos] = make_int2(ei[e], __float_as_int(ew[e]));
}

// Tier-2 reorder (atomic ticket), kept for smaller workspaces.
__global__ __launch_bounds__(256) void reorder_k(
    const int*   __restrict__ ei,
    const float* __restrict__ ew,
    int*         __restrict__ cursor,
    int2*        __restrict__ sorted_e)
{
    int e = blockIdx.x * 256 + threadIdx.x;
    if (e >= N_EDGES) return;
    int src = ei[e];
    int dst = ei[N_EDGES + e];
    int pos = atomicAdd(&cursor[dst], 1);
    sorted_e[pos] = make_int2(src, __float_as_int(ew[e]));
}

// Fused aggregate + residual + GEMM, v2: group-per-node, zero shuffles.
// Each 16-lane group owns one node; all 16 lanes broadcast-load the same
// edge record (4 distinct 8 B addresses per wave), then gather their float4
// chunk of the source row. Loop predication is purely per-lane (no cross-lane
// ops), so group-divergent trip counts are safe — the round-4 lesson.
// 16 nodes/block (4 waves x 4 groups) amortize the W LDS staging.
__global__ __launch_bounds__(256) void agg_gemm_k(
    const float* __restrict__ feat,
    const int2*  __restrict__ sorted_e,
    const int*   __restrict__ offsets,
    const float* __restrict__ W,
    const float* __restrict__ bias,
    float*       __restrict__ out)
{
    constexpr int PITCH = 68;
    constexpr int NPB = 16;
    __shared__ float Wl[D * PITCH];
    __shared__ float xs[NPB][D];

    int tid = threadIdx.x;
    for (int i = tid; i < D * D; i += 256)
        Wl[(i >> 6) * PITCH + (i & 63)] = W[i];

    int lane = tid & 63;
    int wv   = tid >> 6;
    int g    = lane >> 4;   // node-within-wave 0..3
    int sub  = lane & 15;   // float4 chunk 0..15

    int slot = wv * 4 + g;               // 0..15
    int n    = blockIdx.x * NPB + slot;
    int lo = offsets[n], hi = offsets[n + 1];
    int deg = hi - lo;

    // Residual init: wave covers 4 consecutive rows -> contiguous 1 KB load.
    float4 acc = *reinterpret_cast<const float4*>(feat + (size_t)n * D + sub * 4);

    const int2* ep = sorted_e + lo;
#pragma unroll 2
    for (int j = 0; j < deg; ++j) {
        int2  er = ep[j];                 // group-uniform broadcast load
        float w  = __int_as_float(er.y);
        float4 f = *reinterpret_cast<const float4*>(
            feat + (size_t)er.x * D + sub * 4);
        acc.x = fmaf(f.x, w, acc.x);
        acc.y = fmaf(f.y, w, acc.y);
        acc.z = fmaf(f.z, w, acc.z);
        acc.w = fmaf(f.w, w, acc.w);
    }
    *reinterpret_cast<float4*>(&xs[slot][sub * 4]) = acc;
    __syncthreads();

    // GEMM: wave wv computes its 4 nodes, lane = output column.
    const float4* w4 = reinterpret_cast<const float4*>(&Wl[lane * PITCH]);
    const float4* x0 = reinterpret_cast<const float4*>(&xs[wv * 4 + 0][0]);
    const float4* x1 = reinterpret_cast<const float4*>(&xs[wv * 4 + 1][0]);
    const float4* x2 = reinterpret_cast<const float4*>(&xs[wv * 4 + 2][0]);
    const float4* x3 = reinterpret_cast<const float4*>(&xs[wv * 4 + 3][0]);
    float b = bias[lane];
    float a0 = b, a1 = b, a2 = b, a3 = b;
#pragma unroll
    for (int i = 0; i < 16; ++i) {
        float4 wq = w4[i];
        float4 v0 = x0[i];
        float4 v1 = x1[i];
        float4 v2 = x2[i];
        float4 v3 = x3[i];
        a0 += v0.x * wq.x + v0.y * wq.y + v0.z * wq.z + v0.w * wq.w;
        a1 += v1.x * wq.x + v1.y * wq.y + v1.z * wq.z + v1.w * wq.w;
        a2 += v2.x * wq.x + v2.y * wq.y + v2.z * wq.z + v2.w * wq.w;
        a3 += v3.x * wq.x + v3.y * wq.y + v3.z * wq.z + v3.w * wq.w;
    }
    int nb = blockIdx.x * NPB + wv * 4;
    out[(size_t)(nb + 0) * D + lane] = a0;
    out[(size_t)(nb + 1) * D + lane] = a1;
    out[(size_t)(nb + 2) * D + lane] = a2;
    out[(size_t)(nb + 3) * D + lane] = a3;
}

// ---------------- fallback path (round-1, atomic scatter) ------------------

__global__ __launch_bounds__(256) void scatter_k(
    const float* __restrict__ feat,
    const int*   __restrict__ ei,
    const float* __restrict__ ew,
    float*       __restrict__ agg)
{
    int gid = blockIdx.x * 256 + threadIdx.x;
    int e = gid >> 4;
    if (e >= N_EDGES) return;
    int c = (gid & 15) * 4;
    int   src = ei[e];
    int   dst = ei[N_EDGES + e];
    float w   = ew[e];
    float4 f = *reinterpret_cast<const float4*>(feat + (size_t)src * D + c);
    float* a = agg + (size_t)dst * D + c;
    atomicAdd(a + 0, f.x * w);
    atomicAdd(a + 1, f.y * w);
    atomicAdd(a + 2, f.z * w);
    atomicAdd(a + 3, f.w * w);
}

__global__ __launch_bounds__(256) void gemm_k(
    const float* __restrict__ agg,
    const float* __restrict__ feat,
    const float* __restrict__ W,
    const float* __restrict__ bias,
    float*       __restrict__ out)
{
    constexpr int PITCH = 68;
    __shared__ float Wl[D * PITCH];
    __shared__ float xs[4][D];
    int tid = threadIdx.x;
    for (int i = tid; i < D * D; i += 256)
        Wl[(i >> 6) * PITCH + (i & 63)] = W[i];
    int o  = tid & 63;
    int wv = tid >> 6;
    int n  = blockIdx.x * 4 + wv;
    float b = bias[o];
    if (n < N_NODES)
        xs[wv][o] = agg[(size_t)n * D + o] + feat[(size_t)n * D + o];
    __syncthreads();
    if (n >= N_NODES) return;
    const float4* x4 = reinterpret_cast<const float4*>(&xs[wv][0]);
    const float4* w4 = reinterpret_cast<const float4*>(&Wl[o * PITCH]);
    float acc = b;
#pragma unroll
    for (int i = 0; i < 16; ++i) {
        float4 xv = x4[i];
        float4 wq = w4[i];
        acc += xv.x * wq.x + xv.y * wq.y + xv.z * wq.z + xv.w * wq.w;
    }
    out[(size_t)n * D + o] = acc;
}

// ---------------- launch ---------------------------------------------------

extern "C" void kernel_launch(void* const* d_in, const int* in_sizes, int n_in,
                              void* d_out, int out_size, void* d_ws, size_t ws_size,
                              hipStream_t stream) {
    const float* feat = (const float*)d_in[0];
    const int*   ei   = (const int*)d_in[1];   // [2, E]: row 0 = src, row 1 = dst
    const float* ew   = (const float*)d_in[2];
    const float* W    = (const float*)d_in[3];
    const float* b    = (const float*)d_in[4];
    float*       out  = (float*)d_out;

    // ws layout: cnt[NPAD] | offsets[NPAD] | rank[1M] | sorted_e[1M int2]
    // tileSums/tileBase live in cnt[]'s padding (ints 100096.. / 100224..).
    constexpr size_t NPAD       = 100352;
    constexpr size_t CNT_OFF    = 0;
    constexpr size_t OFFSET_OFF = NPAD * sizeof(int);
    constexpr size_t RANK_OFF   = 2 * NPAD * sizeof(int);
    constexpr size_t SORT1_OFF  = RANK_OFF + (size_t)N_EDGES * sizeof(int);
    constexpr size_t WS_RANK    = SORT1_OFF + (size_t)N_EDGES * sizeof(int2);
    constexpr size_t SORT2_OFF  = RANK_OFF;   // tier 2: sorted_e where rank was
    constexpr size_t WS_SORT    = SORT2_OFF + (size_t)N_EDGES * sizeof(int2);

    if (ws_size >= WS_RANK) {
        int*  cnt      = (int*)((char*)d_ws + CNT_OFF);
        int*  offsets  = (int*)((char*)d_ws + OFFSET_OFF);
        int*  rank     = (int*)((char*)d_ws + RANK_OFF);
        int2* sorted_e = (int2*)((char*)d_ws + SORT1_OFF);
        int*  tileSums = cnt + 100096;
        int*  tileBase = cnt + 100224;

        hipMemsetAsync(cnt, 0, N_NODES * sizeof(int), stream);
        rank_k     <<<(N_EDGES + 255) / 256, 256, 0, stream>>>(ei, cnt, rank);
        tile_sum_k <<<NTILES, 256, 0, stream>>>(cnt, tileSums);
        tile_scan_k<<<1, 128, 0, stream>>>(tileSums, tileBase);
        scan_apply_k<<<NTILES, 256, 0, stream>>>(cnt, tileBase, offsets);
        place_k    <<<(N_EDGES + 255) / 256, 256, 0, stream>>>(ei, ew, rank, offsets, sorted_e);
        agg_gemm_k <<<N_NODES / 16, 256, 0, stream>>>(feat, sorted_e, offsets, W, b, out);
    } else if (ws_size >= WS_SORT) {
        int*  cnt      = (int*)((char*)d_ws + CNT_OFF);      // -> cursor after scan
        int*  offsets  = (int*)((char*)d_ws + OFFSET_OFF);
        int2* sorted_e = (int2*)((char*)d_ws + SORT2_OFF);
        int*  tileSums = cnt + 100096;
        int*  tileBase = cnt + 100224;

        hipMemsetAsync(cnt, 0, N_NODES * sizeof(int), stream);
        hist_k     <<<(N_EDGES + 255) / 256, 256, 0, stream>>>(ei, cnt);
        tile_sum_k <<<NTILES, 256, 0, stream>>>(cnt, tileSums);
        tile_scan_k<<<1, 128, 0, stream>>>(tileSums, tileBase);
        scan_apply_k<<<NTILES, 256, 0, stream>>>(cnt, tileBase, offsets);
        reorder_k  <<<(N_EDGES + 255) / 256, 256, 0, stream>>>(ei, ew, cnt, sorted_e);
        agg_gemm_k <<<N_NODES / 16, 256, 0, stream>>>(feat, sorted_e, offsets, W, b, out);
    } else {
        const size_t agg_bytes = (size_t)N_NODES * D * sizeof(float);
        float* agg = (ws_size >= agg_bytes) ? (float*)d_ws : out;
        hipMemsetAsync(agg, 0, agg_bytes, stream);
        scatter_k<<<(N_EDGES * 16) / 256, 256, 0, stream>>>(feat, ei, ew, agg);
        gemm_k<<<(N_NODES + 3) / 4, 256, 0, stream>>>(agg, feat, W, b, out);
    }
}